// Round 3
// baseline (128.026 us; speedup 1.0000x reference)
//
#include <hip/hip_runtime.h>
#include <hip/hip_bf16.h>

// Problem constants: bs=8, Na=128, Nc=256, CS=3, D=H=64, Z=8, NT=3, NET=9
// Output 0: logpi (8,256,8,8,8) f32 = 1048576 elems
// Output 1: z meshgrid (8,8,8,3) -> 1536 elems (float values)

#define BS   8
#define NA   128
#define NC   256
#define DIM  64
#define ZZ   8

// ---------------------------------------------------------------------------
// Kernel A: node MLP, one wave per (b,n). Activation kept in a register;
// broadcast via __shfl (v_readlane, scalar pipe) instead of LDS.
// ---------------------------------------------------------------------------
__global__ __launch_bounds__(64) void node_mlp_kernel(
    const int* __restrict__ nt, const float* __restrict__ enc,
    const float* __restrict__ W0, const float* __restrict__ b0,
    const float* __restrict__ W1, const float* __restrict__ b1,
    const float* __restrict__ W2, const float* __restrict__ b2,
    float* __restrict__ nf /* (BS,NA,ZZ) */) {
  const int blk  = blockIdx.x;      // b*NA + n
  const int lane = threadIdx.x;
  const int t = nt[blk];

  float e = enc[blk * DIM + lane];

  // layer 0
  float acc = b0[t * DIM + lane];
  {
    const float* w = W0 + t * DIM * DIM + lane;
#pragma unroll
    for (int k = 0; k < DIM; ++k) acc = fmaf(__shfl(e, k), w[k * DIM], acc);
  }
  float h = fmaxf(acc, 0.f);

  // layer 1
  acc = b1[t * DIM + lane];
  {
    const float* w = W1 + t * DIM * DIM + lane;
#pragma unroll
    for (int k = 0; k < DIM; ++k) acc = fmaf(__shfl(h, k), w[k * DIM], acc);
  }
  float h1 = fmaxf(acc, 0.f);

  // layer 2: 8 outputs. lane = s*8 + z handles K-slice s for output z,
  // then butterfly-reduce over the 8 slices (stride 8,16,32).
  const int z = lane & 7, s = lane >> 3;
  acc = 0.f;
  {
    const float* w2 = W2 + t * DIM * ZZ + z;
#pragma unroll
    for (int k = 0; k < 8; ++k)
      acc = fmaf(__shfl(h1, s * 8 + k), w2[(s * 8 + k) * ZZ], acc);
  }
  acc += __shfl_xor(acc, 8);
  acc += __shfl_xor(acc, 16);
  acc += __shfl_xor(acc, 32);
  if (lane < ZZ) nf[blk * ZZ + lane] = acc + b2[t * ZZ + lane];
}

// ---------------------------------------------------------------------------
// Kernel B (fused): one 256-thread block per clique.
//   waves 0..2: edge MLP for pair p (shfl matvec, no LDS in the hot loop)
//   wave  3   : gather the 3 node factors
//   barrier, then wave 0 assembles logpi; wave 1 writes the z-meshgrid tail.
// ---------------------------------------------------------------------------
__global__ __launch_bounds__(256) void clique_fused_kernel(
    const int* __restrict__ nt, const int* __restrict__ cni,
    const float* __restrict__ edge_enc, const float* __restrict__ nf,
    const float* __restrict__ eW0, const float* __restrict__ eb0,
    const float* __restrict__ eW1, const float* __restrict__ eb1,
    const float* __restrict__ eW2, const float* __restrict__ eb2,
    float* __restrict__ out) {
  const int blk  = blockIdx.x;     // b*NC + c
  const int tid  = threadIdx.x;
  const int wave = tid >> 6, lane = tid & 63;
  const int b = blk >> 8;

  __shared__ int   idxs[3];
  __shared__ float nfs[3][ZZ];
  __shared__ float ef[3][DIM];

  if (tid < 3) {
    int v = cni[blk * 3 + tid];
    idxs[tid] = (v < 0 || v >= NA) ? NA : v;
  }
  __syncthreads();

  if (wave == 3) {
    if (lane < 3 * ZZ) {
      const int i = lane >> 3, z = lane & 7, v = idxs[i];
      nfs[i][z] = (v < NA) ? nf[(b * NA + v) * ZZ + z] : 0.f;
    }
  } else {
    const int p = wave;                       // pair index
    const int pi = (p == 2) ? 1 : 0;
    const int pj = (p == 0) ? 1 : 2;
    const int ia = idxs[pi], jb = idxs[pj];
    if (ia >= NA || jb >= NA) {               // wave-uniform
      ef[p][lane] = 0.f;
    } else {
      const int t = nt[b * NA + jb] * 3 + nt[b * NA + ia];
      float e = edge_enc[((b * NA + ia) * NA + jb) * DIM + lane];

      // layer 0
      float acc = eb0[t * DIM + lane];
      {
        const float* w = eW0 + t * DIM * DIM + lane;
#pragma unroll
        for (int k = 0; k < DIM; ++k) acc = fmaf(__shfl(e, k), w[k * DIM], acc);
      }
      e = fmaxf(acc, 0.f);

      // layer 1
      acc = eb1[t * DIM + lane];
      {
        const float* w = eW1 + t * DIM * DIM + lane;
#pragma unroll
        for (int k = 0; k < DIM; ++k) acc = fmaf(__shfl(e, k), w[k * DIM], acc);
      }
      e = fmaxf(acc, 0.f);

      // layer 2 (no relu)
      acc = eb2[t * DIM + lane];
      {
        const float* w = eW2 + t * DIM * DIM + lane;
#pragma unroll
        for (int k = 0; k < DIM; ++k) acc = fmaf(__shfl(e, k), w[k * DIM], acc);
      }
      ef[p][lane] = acc;
    }
  }
  __syncthreads();

  if (wave == 0) {
    // lane = z1*8+z2, loop over z0 (8 coalesced 256B stores)
    const int z1 = lane >> 3, z2 = lane & 7;
    const float base = nfs[1][z1] + nfs[2][z2] + ef[2][z1 * ZZ + z2];
    float* o = out + blk * (ZZ * ZZ * ZZ);
#pragma unroll
    for (int z0 = 0; z0 < ZZ; ++z0) {
      o[z0 * 64 + lane] = base + nfs[0][z0] + ef[0][z0 * ZZ + z1] + ef[1][z0 * ZZ + z2];
    }
  } else if (wave == 1 && blk < 24) {
    // z meshgrid tail: 1536 elems = 24 blocks * 64 lanes
    const int i = blk * 64 + lane;
    const int k = i % 3;
    const int r = i / 3;               // z0*64 + z1*8 + z2
    const int zz2 = r & 7, zz1 = (r >> 3) & 7, zz0 = r >> 6;
    const int v = (k == 0) ? zz0 : ((k == 1) ? zz1 : zz2);
    out[BS * NC * ZZ * ZZ * ZZ + i] = (float)v;
  }
}

extern "C" void kernel_launch(void* const* d_in, const int* in_sizes, int n_in,
                              void* d_out, int out_size, void* d_ws, size_t ws_size,
                              hipStream_t stream) {
  const int*   node_types = (const int*)  d_in[0];
  const float* node_enc   = (const float*)d_in[1];
  const float* edge_enc   = (const float*)d_in[2];
  const int*   cni        = (const int*)  d_in[4];
  const float* nW0 = (const float*)d_in[6];
  const float* nb0 = (const float*)d_in[7];
  const float* nW1 = (const float*)d_in[8];
  const float* nb1 = (const float*)d_in[9];
  const float* nW2 = (const float*)d_in[10];
  const float* nb2 = (const float*)d_in[11];
  const float* eW0 = (const float*)d_in[12];
  const float* eb0 = (const float*)d_in[13];
  const float* eW1 = (const float*)d_in[14];
  const float* eb1 = (const float*)d_in[15];
  const float* eW2 = (const float*)d_in[16];
  const float* eb2 = (const float*)d_in[17];

  float* out = (float*)d_out;
  float* node_factor = (float*)d_ws;   // 8*128*8 f32 = 32 KB

  node_mlp_kernel<<<BS * NA, 64, 0, stream>>>(
      node_types, node_enc, nW0, nb0, nW1, nb1, nW2, nb2, node_factor);

  clique_fused_kernel<<<BS * NC, 256, 0, stream>>>(
      node_types, cni, edge_enc, node_factor,
      eW0, eb0, eW1, eb1, eW2, eb2, out);
}